// Round 1
// baseline (2048.800 us; speedup 1.0000x reference)
//
#include <hip/hip_runtime.h>
#include <math.h>

// GraphSAGE 2-layer, mean aggregation, fp32.
// out = log_softmax( sage2( relu( sage1(x) ) ) )
// sage(x) = mean_agg(x) @ w_l + x @ w_r + b
//
// Optimization: mean-aggregation commutes with the linear projection, so
//  layer 1 aggregates in IN_C=19 dims (raw x), layer 2 aggregates in
//  OUT_C=4 dims (after projecting h @ w2_l). h ([N,128]) is never stored:
//  the fused per-node kernel computes h in LDS and immediately reduces it
//  to g = h@w2_l and s = h@w2_r.

constexpr int N    = 100000;
constexpr int E    = 1600000;
constexpr int INC  = 19;
constexpr int HID  = 128;
constexpr int OUTC = 4;

// ---- kernel 0: detect whether edge_index arrived as int64 or int32 -------
// int64 little-endian with values < 2^17: every odd 32-bit word is 0.
// int32 layout: odd words are random node ids -> essentially never all 0.
__global__ void detect_idx64(const int* __restrict__ ei, int* __restrict__ flag) {
    __shared__ int any;
    if (threadIdx.x == 0) any = 0;
    __syncthreads();
    int v = 0;
    for (int k = threadIdx.x; k < 1024; k += blockDim.x)
        v |= ei[2 * k + 1];
    if (v) atomicOr(&any, 1);
    __syncthreads();
    if (threadIdx.x == 0) *flag = (any == 0) ? 1 : 0;
}

__device__ inline void load_edge(const int* __restrict__ ei, int e, int is64,
                                 int& src, int& dst) {
    if (is64) {
        src = ei[2 * e];          // low word of element (0, e)
        dst = ei[2 * E + 2 * e];  // low word of element (1, e)
    } else {
        src = ei[e];
        dst = ei[E + e];
    }
}

// ---- kernel 1: degree count + layer-1 aggregation (19 dims) --------------
__global__ void deg_agg1_kernel(const int* __restrict__ ei,
                                const float* __restrict__ x,
                                float* __restrict__ cnt,
                                float* __restrict__ agg1,
                                const int* __restrict__ flag) {
    int e = blockIdx.x * blockDim.x + threadIdx.x;
    if (e >= E) return;
    int is64 = *flag;
    int src, dst;
    load_edge(ei, e, is64, src, dst);
    atomicAdd(&cnt[dst], 1.0f);
    const float* xr = x + (size_t)src * INC;
    float* ar = agg1 + (size_t)dst * INC;
#pragma unroll
    for (int c = 0; c < INC; ++c)
        atomicAdd(&ar[c], xr[c]);
}

// ---- kernel 2: fused  h = relu(mean1@w1l + x@w1r + b1); g = h@w2l; s = h@w2r
// one block (128 threads) per node
__global__ void l1_fused_kernel(const float* __restrict__ x,
                                const float* __restrict__ agg1,
                                const float* __restrict__ cnt,
                                const float* __restrict__ w1l,
                                const float* __restrict__ w1r,
                                const float* __restrict__ b1,
                                const float* __restrict__ w2l,
                                const float* __restrict__ w2r,
                                float* __restrict__ g,
                                float* __restrict__ s) {
    int i = blockIdx.x;
    int t = threadIdx.x;
    __shared__ float xs[INC];
    __shared__ float ms[INC];
    __shared__ float hs[HID];

    if (t < INC) {
        float inv = 1.0f / fmaxf(cnt[i], 1.0f);
        xs[t] = x[(size_t)i * INC + t];
        ms[t] = agg1[(size_t)i * INC + t] * inv;
    }
    __syncthreads();

    float acc = b1[t];
#pragma unroll
    for (int c = 0; c < INC; ++c)
        acc += ms[c] * w1l[c * HID + t] + xs[c] * w1r[c * HID + t];
    hs[t] = fmaxf(acc, 0.0f);
    __syncthreads();

    // 8 dot products of length 128: wave 0 -> w2l (g), wave 1 -> w2r (s)
    const float* w2 = (t < 64) ? w2l : w2r;
    int l = t & 63;
    float a0 = 0.f, a1 = 0.f, a2 = 0.f, a3 = 0.f;
#pragma unroll
    for (int c = l; c < HID; c += 64) {
        float hv = hs[c];
        a0 += hv * w2[c * OUTC + 0];
        a1 += hv * w2[c * OUTC + 1];
        a2 += hv * w2[c * OUTC + 2];
        a3 += hv * w2[c * OUTC + 3];
    }
#pragma unroll
    for (int o = 32; o; o >>= 1) {
        a0 += __shfl_down(a0, o);
        a1 += __shfl_down(a1, o);
        a2 += __shfl_down(a2, o);
        a3 += __shfl_down(a3, o);
    }
    if (l == 0) {
        float* outp = (t < 64) ? (g + (size_t)i * OUTC) : (s + (size_t)i * OUTC);
        outp[0] = a0; outp[1] = a1; outp[2] = a2; outp[3] = a3;
    }
}

// ---- kernel 3: layer-2 aggregation (4 dims) -------------------------------
__global__ void agg2_kernel(const int* __restrict__ ei,
                            const float* __restrict__ g,
                            float* __restrict__ agg2,
                            const int* __restrict__ flag) {
    int e = blockIdx.x * blockDim.x + threadIdx.x;
    if (e >= E) return;
    int is64 = *flag;
    int src, dst;
    load_edge(ei, e, is64, src, dst);
    const float4 gv = *(const float4*)(g + (size_t)src * OUTC);
    float* ar = agg2 + (size_t)dst * OUTC;
    atomicAdd(&ar[0], gv.x);
    atomicAdd(&ar[1], gv.y);
    atomicAdd(&ar[2], gv.z);
    atomicAdd(&ar[3], gv.w);
}

// ---- kernel 4: mean + self + bias + log_softmax ---------------------------
__global__ void final_kernel(const float* __restrict__ agg2,
                             const float* __restrict__ cnt,
                             const float* __restrict__ s,
                             const float* __restrict__ b2,
                             float* __restrict__ out) {
    int i = blockIdx.x * blockDim.x + threadIdx.x;
    if (i >= N) return;
    float inv = 1.0f / fmaxf(cnt[i], 1.0f);
    float o[OUTC];
#pragma unroll
    for (int k = 0; k < OUTC; ++k)
        o[k] = agg2[(size_t)i * OUTC + k] * inv + s[(size_t)i * OUTC + k] + b2[k];
    float m = fmaxf(fmaxf(o[0], o[1]), fmaxf(o[2], o[3]));
    float sum = 0.f;
#pragma unroll
    for (int k = 0; k < OUTC; ++k)
        sum += expf(o[k] - m);
    float lse = logf(sum);
#pragma unroll
    for (int k = 0; k < OUTC; ++k)
        out[(size_t)i * OUTC + k] = o[k] - m - lse;
}

extern "C" void kernel_launch(void* const* d_in, const int* in_sizes, int n_in,
                              void* d_out, int out_size, void* d_ws, size_t ws_size,
                              hipStream_t stream) {
    const float* x   = (const float*)d_in[0];
    const int*   ei  = (const int*)d_in[1];
    const float* w1l = (const float*)d_in[2];
    const float* w1r = (const float*)d_in[3];
    const float* b1  = (const float*)d_in[4];
    const float* w2l = (const float*)d_in[5];
    const float* w2r = (const float*)d_in[6];
    const float* b2  = (const float*)d_in[7];
    float* out = (float*)d_out;

    // workspace layout (floats): [flag pad 64][cnt N][agg1 19N][g 4N][s 4N][agg2 4N]
    float* ws   = (float*)d_ws;
    int*   flag = (int*)ws;
    float* cnt  = ws + 64;
    float* agg1 = cnt + N;
    float* g    = agg1 + (size_t)N * INC;
    float* s    = g + (size_t)N * OUTC;
    float* agg2 = s + (size_t)N * OUTC;

    // zero the accumulators (every call: must be deterministic, ws is not re-poisoned)
    hipMemsetAsync(cnt, 0, (size_t)(N + (size_t)N * INC) * sizeof(float), stream);
    hipMemsetAsync(agg2, 0, (size_t)N * OUTC * sizeof(float), stream);

    detect_idx64<<<1, 256, 0, stream>>>(ei, flag);
    deg_agg1_kernel<<<(E + 255) / 256, 256, 0, stream>>>(ei, x, cnt, agg1, flag);
    l1_fused_kernel<<<N, HID, 0, stream>>>(x, agg1, cnt, w1l, w1r, b1, w2l, w2r, g, s);
    agg2_kernel<<<(E + 255) / 256, 256, 0, stream>>>(ei, g, agg2, flag);
    final_kernel<<<(N + 255) / 256, 256, 0, stream>>>(agg2, cnt, s, b2, out);
}

// Round 2
// 358.073 us; speedup vs baseline: 5.7217x; 5.7217x over previous
//
#include <hip/hip_runtime.h>
#include <math.h>

// GraphSAGE 2-layer, mean aggregation, fp32.
// Round 2: replace scatter-atomics (32M fp32 atomicAdds -> 1GB of memory-side
// atomic write traffic, the R1 bottleneck) with a per-call CSR build
// (counting sort: 3.2M int atomics) + gather-based aggregation (no atomics).
// Layer-1 gather (19 dims) is fused into the l1 matmul kernel; layer-2
// gather (4 dims) is fused into the final log_softmax kernel.

constexpr int N    = 100000;
constexpr int E    = 1600000;
constexpr int INC  = 19;
constexpr int HID  = 128;
constexpr int OUTC = 4;
constexpr int NB   = (N + 255) / 256;   // 391 scan blocks

// ---- kernel 0: detect whether edge_index arrived as int64 or int32 -------
__global__ void detect_idx64(const int* __restrict__ ei, int* __restrict__ flag) {
    __shared__ int any;
    if (threadIdx.x == 0) any = 0;
    __syncthreads();
    int v = 0;
    for (int k = threadIdx.x; k < 1024; k += blockDim.x)
        v |= ei[2 * k + 1];
    if (v) atomicOr(&any, 1);
    __syncthreads();
    if (threadIdx.x == 0) *flag = (any == 0) ? 1 : 0;
}

__device__ inline void load_edge(const int* __restrict__ ei, int e, int is64,
                                 int& src, int& dst) {
    if (is64) {
        src = ei[2 * e];          // low word of element (0, e)
        dst = ei[2 * E + 2 * e];  // low word of element (1, e)
    } else {
        src = ei[e];
        dst = ei[E + e];
    }
}

// ---- kernel 1: degree histogram -------------------------------------------
__global__ void deg_kernel(const int* __restrict__ ei, int* __restrict__ deg,
                           const int* __restrict__ flag) {
    int e = blockIdx.x * blockDim.x + threadIdx.x;
    if (e >= E) return;
    int is64 = *flag;
    int src, dst;
    load_edge(ei, e, is64, src, dst);
    atomicAdd(&deg[dst], 1);
}

// ---- kernels 2a/2b/2c: exclusive scan of deg -> cursor (global starts) ----
__global__ void scan_block(const int* __restrict__ deg, int* __restrict__ cursor,
                           int* __restrict__ bsum) {
    __shared__ int sd[256];
    int t = threadIdx.x;
    int i = blockIdx.x * 256 + t;
    int v = (i < N) ? deg[i] : 0;
    sd[t] = v;
    __syncthreads();
    for (int off = 1; off < 256; off <<= 1) {
        int add = (t >= off) ? sd[t - off] : 0;
        __syncthreads();
        sd[t] += add;
        __syncthreads();
    }
    if (i < N) cursor[i] = sd[t] - v;              // block-local exclusive
    if (t == 255) bsum[blockIdx.x] = sd[255];      // block total
}

__global__ void scan_bsum(int* __restrict__ bsum) {
    __shared__ int sd[512];
    int t = threadIdx.x;
    int v = (t < NB) ? bsum[t] : 0;
    sd[t] = v;
    __syncthreads();
    for (int off = 1; off < 512; off <<= 1) {
        int add = (t >= off) ? sd[t - off] : 0;
        __syncthreads();
        sd[t] += add;
        __syncthreads();
    }
    if (t < NB) bsum[t] = sd[t] - v;               // exclusive block bases
}

__global__ void scan_addback(int* __restrict__ cursor, const int* __restrict__ bsum) {
    int i = blockIdx.x * 256 + threadIdx.x;
    if (i < N) cursor[i] += bsum[blockIdx.x];
}

// ---- kernel 3: scatter edges into CSR buckets -----------------------------
// after this, cursor[i] == start_i + deg_i == end_i
__global__ void scatter_kernel(const int* __restrict__ ei, int* __restrict__ cursor,
                               int* __restrict__ adj, const int* __restrict__ flag) {
    int e = blockIdx.x * blockDim.x + threadIdx.x;
    if (e >= E) return;
    int is64 = *flag;
    int src, dst;
    load_edge(ei, e, is64, src, dst);
    int pos = atomicAdd(&cursor[dst], 1);
    adj[pos] = src;
}

// ---- kernel 4: fused  mean1 = gather-mean(x); h = relu(mean1@w1l + x@w1r + b1);
//                g = h@w2l; s = h@w2r          (one block of 128 per node)
__global__ void l1_fused_kernel(const float* __restrict__ x,
                                const int* __restrict__ adj,
                                const int* __restrict__ cursor,
                                const int* __restrict__ deg,
                                const float* __restrict__ w1l,
                                const float* __restrict__ w1r,
                                const float* __restrict__ b1,
                                const float* __restrict__ w2l,
                                const float* __restrict__ w2r,
                                float* __restrict__ g,
                                float* __restrict__ s) {
    int i = blockIdx.x;
    int t = threadIdx.x;
    __shared__ float part[4][INC];
    __shared__ float xs[INC];
    __shared__ float ms[INC];
    __shared__ float hs[HID];

    int d  = deg[i];
    int st = cursor[i] - d;
    int grp = t >> 5, ln = t & 31;

    // neighbor gather: 4 lane-groups stride the neighbor list, 19 lanes/row
    if (ln < INC) {
        float a = 0.f;
        for (int j = grp; j < d; j += 4) {
            int sn = adj[st + j];
            a += x[(size_t)sn * INC + ln];
        }
        part[grp][ln] = a;
    }
    if (t < INC) xs[t] = x[(size_t)i * INC + t];
    __syncthreads();
    if (t < INC) {
        float inv = 1.0f / fmaxf((float)d, 1.0f);
        ms[t] = (part[0][t] + part[1][t] + part[2][t] + part[3][t]) * inv;
    }
    __syncthreads();

    float acc = b1[t];
#pragma unroll
    for (int c = 0; c < INC; ++c)
        acc += ms[c] * w1l[c * HID + t] + xs[c] * w1r[c * HID + t];
    hs[t] = fmaxf(acc, 0.0f);
    __syncthreads();

    // 8 dot products of length 128: wave 0 -> w2l (g), wave 1 -> w2r (s)
    const float* w2 = (t < 64) ? w2l : w2r;
    int l = t & 63;
    float a0 = 0.f, a1 = 0.f, a2 = 0.f, a3 = 0.f;
#pragma unroll
    for (int c = l; c < HID; c += 64) {
        float hv = hs[c];
        a0 += hv * w2[c * OUTC + 0];
        a1 += hv * w2[c * OUTC + 1];
        a2 += hv * w2[c * OUTC + 2];
        a3 += hv * w2[c * OUTC + 3];
    }
#pragma unroll
    for (int o = 32; o; o >>= 1) {
        a0 += __shfl_down(a0, o);
        a1 += __shfl_down(a1, o);
        a2 += __shfl_down(a2, o);
        a3 += __shfl_down(a3, o);
    }
    if (l == 0) {
        float* outp = (t < 64) ? (g + (size_t)i * OUTC) : (s + (size_t)i * OUTC);
        outp[0] = a0; outp[1] = a1; outp[2] = a2; outp[3] = a3;
    }
}

// ---- kernel 5: gather-mean(g) + self + bias + log_softmax -----------------
__global__ void final_kernel(const float* __restrict__ g,
                             const int* __restrict__ adj,
                             const int* __restrict__ cursor,
                             const int* __restrict__ deg,
                             const float* __restrict__ s,
                             const float* __restrict__ b2,
                             float* __restrict__ out) {
    int i = blockIdx.x * blockDim.x + threadIdx.x;
    if (i >= N) return;
    int d  = deg[i];
    int st = cursor[i] - d;
    float4 acc = make_float4(0.f, 0.f, 0.f, 0.f);
    for (int j = 0; j < d; ++j) {
        int sn = adj[st + j];
        float4 gv = *(const float4*)(g + (size_t)sn * OUTC);
        acc.x += gv.x; acc.y += gv.y; acc.z += gv.z; acc.w += gv.w;
    }
    float inv = 1.0f / fmaxf((float)d, 1.0f);
    float o[OUTC];
    o[0] = acc.x * inv + s[(size_t)i * OUTC + 0] + b2[0];
    o[1] = acc.y * inv + s[(size_t)i * OUTC + 1] + b2[1];
    o[2] = acc.z * inv + s[(size_t)i * OUTC + 2] + b2[2];
    o[3] = acc.w * inv + s[(size_t)i * OUTC + 3] + b2[3];
    float m = fmaxf(fmaxf(o[0], o[1]), fmaxf(o[2], o[3]));
    float sum = 0.f;
#pragma unroll
    for (int k = 0; k < OUTC; ++k)
        sum += expf(o[k] - m);
    float lse = logf(sum);
    float4 ov = make_float4(o[0] - m - lse, o[1] - m - lse, o[2] - m - lse, o[3] - m - lse);
    *(float4*)(out + (size_t)i * OUTC) = ov;
}

extern "C" void kernel_launch(void* const* d_in, const int* in_sizes, int n_in,
                              void* d_out, int out_size, void* d_ws, size_t ws_size,
                              hipStream_t stream) {
    const float* x   = (const float*)d_in[0];
    const int*   ei  = (const int*)d_in[1];
    const float* w1l = (const float*)d_in[2];
    const float* w1r = (const float*)d_in[3];
    const float* b1  = (const float*)d_in[4];
    const float* w2l = (const float*)d_in[5];
    const float* w2r = (const float*)d_in[6];
    const float* b2  = (const float*)d_in[7];
    float* out = (float*)d_out;

    // workspace layout (4B units):
    // [flag 64][deg N][cursor N][bsum 512][adj E][g 4N][s 4N]
    int*   ws     = (int*)d_ws;
    int*   flag   = ws;
    int*   deg    = ws + 64;
    int*   cursor = deg + N;
    int*   bsum   = cursor + N;
    int*   adj    = bsum + 512;
    float* g      = (float*)(adj + E);
    float* s      = g + (size_t)N * OUTC;

    hipMemsetAsync(deg, 0, (size_t)N * sizeof(int), stream);

    detect_idx64<<<1, 256, 0, stream>>>(ei, flag);
    deg_kernel<<<(E + 255) / 256, 256, 0, stream>>>(ei, deg, flag);
    scan_block<<<NB, 256, 0, stream>>>(deg, cursor, bsum);
    scan_bsum<<<1, 512, 0, stream>>>(bsum);
    scan_addback<<<NB, 256, 0, stream>>>(cursor, bsum);
    scatter_kernel<<<(E + 255) / 256, 256, 0, stream>>>(ei, cursor, adj, flag);
    l1_fused_kernel<<<N, HID, 0, stream>>>(x, adj, cursor, deg, w1l, w1r, b1, w2l, w2r, g, s);
    final_kernel<<<(N + 255) / 256, 256, 0, stream>>>(g, adj, cursor, deg, s, b2, out);
}

// Round 4
// 286.195 us; speedup vs baseline: 7.1588x; 1.2511x over previous
//
#include <hip/hip_runtime.h>
#include <math.h>

// GraphSAGE 2-layer, mean aggregation, fp32.
// Round 4: R3 failed numerically (absmax 0.14) after 3 simultaneous rewrites.
// This round keeps ONLY the provably-equivalent piece (rank-based atomic-free
// scatter: identical adjacency sets as the R2 cursor version) and reverts the
// per-node math of l1/final to R2's verbatim (passing) form. R2's l1
// bottleneck (per-block weight re-reads from L2) is fixed conservatively:
// w1 cached in LDS once per block, w2 in 8 regs/thread, grid-stride blocks
// processing 2 nodes per iteration (one per 128-thread half-block).

constexpr int N    = 100000;
constexpr int E    = 1600000;
constexpr int INC  = 19;
constexpr int HID  = 128;
constexpr int OUTC = 4;
constexpr int NB   = (N + 255) / 256;   // 391 scan blocks

// ---- kernel 0: detect whether edge_index arrived as int64 or int32 -------
__global__ void detect_idx64(const int* __restrict__ ei, int* __restrict__ flag) {
    __shared__ int any;
    if (threadIdx.x == 0) any = 0;
    __syncthreads();
    int v = 0;
    for (int k = threadIdx.x; k < 1024; k += blockDim.x)
        v |= ei[2 * k + 1];
    if (v) atomicOr(&any, 1);
    __syncthreads();
    if (threadIdx.x == 0) *flag = (any == 0) ? 1 : 0;
}

__device__ inline void load_edge(const int* __restrict__ ei, int e, int is64,
                                 int& src, int& dst) {
    if (is64) {
        src = ei[2 * e];
        dst = ei[2 * E + 2 * e];
    } else {
        src = ei[e];
        dst = ei[E + e];
    }
}

// ---- kernel 1: degree histogram + per-edge rank ---------------------------
__global__ void deg_rank_kernel(const int* __restrict__ ei, int* __restrict__ deg,
                                int* __restrict__ rank, const int* __restrict__ flag) {
    int e = blockIdx.x * blockDim.x + threadIdx.x;
    if (e >= E) return;
    int is64 = *flag;
    int dst = is64 ? ei[2 * E + 2 * e] : ei[E + e];
    rank[e] = atomicAdd(&deg[dst], 1);
}

// ---- kernels 2a/2b/2c: exclusive scan of deg -> start ----------------------
__global__ void scan_block(const int* __restrict__ deg, int* __restrict__ start,
                           int* __restrict__ bsum) {
    __shared__ int sd[256];
    int t = threadIdx.x;
    int i = blockIdx.x * 256 + t;
    int v = (i < N) ? deg[i] : 0;
    sd[t] = v;
    __syncthreads();
    for (int off = 1; off < 256; off <<= 1) {
        int add = (t >= off) ? sd[t - off] : 0;
        __syncthreads();
        sd[t] += add;
        __syncthreads();
    }
    if (i < N) start[i] = sd[t] - v;
    if (t == 255) bsum[blockIdx.x] = sd[255];
}

__global__ void scan_bsum(int* __restrict__ bsum) {
    __shared__ int sd[512];
    int t = threadIdx.x;
    int v = (t < NB) ? bsum[t] : 0;
    sd[t] = v;
    __syncthreads();
    for (int off = 1; off < 512; off <<= 1) {
        int add = (t >= off) ? sd[t - off] : 0;
        __syncthreads();
        sd[t] += add;
        __syncthreads();
    }
    if (t < NB) bsum[t] = sd[t] - v;
}

__global__ void scan_addback(int* __restrict__ start, const int* __restrict__ bsum) {
    int i = blockIdx.x * 256 + threadIdx.x;
    if (i < N) start[i] += bsum[blockIdx.x];
}

// ---- kernel 3: atomic-free scatter into CSR -------------------------------
__global__ void scatter_kernel(const int* __restrict__ ei, const int* __restrict__ start,
                               const int* __restrict__ rank, int* __restrict__ adj,
                               const int* __restrict__ flag) {
    int e = blockIdx.x * blockDim.x + threadIdx.x;
    if (e >= E) return;
    int is64 = *flag;
    int src, dst;
    load_edge(ei, e, is64, src, dst);
    adj[start[dst] + rank[e]] = src;
}

// ---- kernel 4: fused layer1 + layer2 projection ---------------------------
// R2's per-node math verbatim; 256-thread block = 2 nodes per iteration
// (half-block each), w1 cached in LDS once per block, w2 in registers.
__global__ __launch_bounds__(256) void l1_fused_v3(
        const float* __restrict__ x,
        const int* __restrict__ adj,
        const int* __restrict__ start,
        const int* __restrict__ deg,
        const float* __restrict__ w1l,
        const float* __restrict__ w1r,
        const float* __restrict__ b1,
        const float* __restrict__ w2l,
        const float* __restrict__ w2r,
        float* __restrict__ g,
        float* __restrict__ s) {
    __shared__ float W1L[INC * HID];
    __shared__ float W1R[INC * HID];
    __shared__ float part[2][4][INC];
    __shared__ float xs[2][INC];
    __shared__ float ms[2][INC];
    __shared__ float hs[2][HID];

    int t   = threadIdx.x;     // 0..255
    int sub = t >> 7;          // which half-block (node slot)
    int tt  = t & 127;         // thread-in-slot

    // cache weights: w1 -> LDS, w2 -> 8 regs/thread, b1 -> 1 reg
    for (int k = t; k < INC * HID; k += 256) {
        W1L[k] = w1l[k];
        W1R[k] = w1r[k];
    }
    float bb = b1[tt];
    const float* w2p = (tt < 64) ? w2l : w2r;
    int l = tt & 63;
    float w2reg[8];
#pragma unroll
    for (int k = 0; k < OUTC; ++k) {
        w2reg[k]     = w2p[l * OUTC + k];
        w2reg[4 + k] = w2p[(l + 64) * OUTC + k];
    }
    __syncthreads();

    int grp = tt >> 5, ln = tt & 31;

    for (int base = blockIdx.x * 2; base < N; base += gridDim.x * 2) {
        int node = base + sub;
        int d = 0, st = 0;
        if (node < N) { d = deg[node]; st = start[node]; }

        // gather (R2 verbatim): 4 groups of 32 lanes, 19 active lanes each
        if (node < N && ln < INC) {
            float a = 0.f;
            for (int j = grp; j < d; j += 4) {
                int sn = adj[st + j];
                a += x[(size_t)sn * INC + ln];
            }
            part[sub][grp][ln] = a;
        }
        if (node < N && tt < INC) xs[sub][tt] = x[(size_t)node * INC + tt];
        __syncthreads();
        if (node < N && tt < INC) {
            float inv = 1.0f / fmaxf((float)d, 1.0f);
            ms[sub][tt] = (part[sub][0][tt] + part[sub][1][tt] +
                           part[sub][2][tt] + part[sub][3][tt]) * inv;
        }
        __syncthreads();

        // layer-1 matmul (R2 verbatim, weights from LDS)
        float acc = bb;
#pragma unroll
        for (int c = 0; c < INC; ++c)
            acc += ms[sub][c] * W1L[c * HID + tt] + xs[sub][c] * W1R[c * HID + tt];
        hs[sub][tt] = fmaxf(acc, 0.0f);
        __syncthreads();

        // layer-2 projection (R2 verbatim): c = l and l+64
        float a0, a1, a2, a3;
        {
            float hv = hs[sub][l];
            a0 = hv * w2reg[0]; a1 = hv * w2reg[1];
            a2 = hv * w2reg[2]; a3 = hv * w2reg[3];
            hv = hs[sub][l + 64];
            a0 += hv * w2reg[4]; a1 += hv * w2reg[5];
            a2 += hv * w2reg[6]; a3 += hv * w2reg[7];
        }
#pragma unroll
        for (int o = 32; o; o >>= 1) {
            a0 += __shfl_down(a0, o);
            a1 += __shfl_down(a1, o);
            a2 += __shfl_down(a2, o);
            a3 += __shfl_down(a3, o);
        }
        if (l == 0 && node < N) {
            float* outp = (tt < 64) ? (g + (size_t)node * OUTC)
                                    : (s + (size_t)node * OUTC);
            outp[0] = a0; outp[1] = a1; outp[2] = a2; outp[3] = a3;
        }
        __syncthreads();   // protect part/xs/ms/hs before next iteration
    }
}

// ---- kernel 5: gather-mean(g) + self + bias + log_softmax (R2 verbatim) ---
__global__ void final_kernel(const float* __restrict__ g,
                             const int* __restrict__ adj,
                             const int* __restrict__ start,
                             const int* __restrict__ deg,
                             const float* __restrict__ s,
                             const float* __restrict__ b2,
                             float* __restrict__ out) {
    int i = blockIdx.x * blockDim.x + threadIdx.x;
    if (i >= N) return;
    int d  = deg[i];
    int st = start[i];
    float4 acc = make_float4(0.f, 0.f, 0.f, 0.f);
    for (int j = 0; j < d; ++j) {
        int sn = adj[st + j];
        float4 gv = *(const float4*)(g + (size_t)sn * OUTC);
        acc.x += gv.x; acc.y += gv.y; acc.z += gv.z; acc.w += gv.w;
    }
    float inv = 1.0f / fmaxf((float)d, 1.0f);
    float o[OUTC];
    o[0] = acc.x * inv + s[(size_t)i * OUTC + 0] + b2[0];
    o[1] = acc.y * inv + s[(size_t)i * OUTC + 1] + b2[1];
    o[2] = acc.z * inv + s[(size_t)i * OUTC + 2] + b2[2];
    o[3] = acc.w * inv + s[(size_t)i * OUTC + 3] + b2[3];
    float m = fmaxf(fmaxf(o[0], o[1]), fmaxf(o[2], o[3]));
    float sum = 0.f;
#pragma unroll
    for (int k = 0; k < OUTC; ++k)
        sum += expf(o[k] - m);
    float lse = logf(sum);
    float4 ov = make_float4(o[0] - m - lse, o[1] - m - lse,
                            o[2] - m - lse, o[3] - m - lse);
    *(float4*)(out + (size_t)i * OUTC) = ov;
}

extern "C" void kernel_launch(void* const* d_in, const int* in_sizes, int n_in,
                              void* d_out, int out_size, void* d_ws, size_t ws_size,
                              hipStream_t stream) {
    const float* x   = (const float*)d_in[0];
    const int*   ei  = (const int*)d_in[1];
    const float* w1l = (const float*)d_in[2];
    const float* w1r = (const float*)d_in[3];
    const float* b1  = (const float*)d_in[4];
    const float* w2l = (const float*)d_in[5];
    const float* w2r = (const float*)d_in[6];
    const float* b2  = (const float*)d_in[7];
    float* out = (float*)d_out;

    // workspace layout (4B units):
    // [flag 64][deg N][start N][bsum 512][adj E][rank E | (g 4N)(s 4N) after scatter]
    int*   ws    = (int*)d_ws;
    int*   flag  = ws;
    int*   deg   = ws + 64;
    int*   start = deg + N;
    int*   bsum  = start + N;
    int*   adj   = bsum + 512;
    int*   rank  = adj + E;
    float* g     = (float*)rank;          // rank dead after scatter; reuse
    float* s     = g + (size_t)N * OUTC;

    hipMemsetAsync(deg, 0, (size_t)N * sizeof(int), stream);

    detect_idx64<<<1, 256, 0, stream>>>(ei, flag);
    deg_rank_kernel<<<(E + 255) / 256, 256, 0, stream>>>(ei, deg, rank, flag);
    scan_block<<<NB, 256, 0, stream>>>(deg, start, bsum);
    scan_bsum<<<1, 512, 0, stream>>>(bsum);
    scan_addback<<<NB, 256, 0, stream>>>(start, bsum);
    scatter_kernel<<<(E + 255) / 256, 256, 0, stream>>>(ei, start, rank, adj, flag);
    l1_fused_v3<<<1792, 256, 0, stream>>>(x, adj, start, deg, w1l, w1r, b1, w2l, w2r, g, s);
    final_kernel<<<(N + 255) / 256, 256, 0, stream>>>(g, adj, start, deg, s, b2, out);
}